// Round 1
// 466.210 us; speedup vs baseline: 1.3314x; 1.3314x over previous
//
#include <hip/hip_runtime.h>
#include <stdint.h>

// Problem constants (fp32 everywhere)
#define NPOS 2394          // 38*63
#define CIN 512
#define KK 4608            // 512*9
#define NANCH 21546        // NPOS*9
#define PRE 6000
#define POST 300
#define NWORD 94           // ceil(6000/64)
#define NQ 8
#define QLEN 2694          // ceil(21546/8)
#define FEATT_BYTES 4902912   // NPOS*512*4

// ---- d_out scratch map (bytes). out bytes = 30,105,600.
#define OFF_BH    0                  // fp16 weight hi plane  [512][4608] = 4,718,592
#define OFF_BL    4718592            // fp16 weight lo plane
#define OFF_P0    9437184
#define OFF_SBOX  9437184            // aliases dead P0
#define OFF_KEEP  9533440
#define OFF_P1    14340096
#define OFF_KEYS  19243008
#define OFF_PROP  19415552
#define OFF_RPART 19760384
#define OFF_FPH   20450048           // fp16 padded feat hi [41][65][512] = 2,728,960
#define OFF_FPL   23179264           // fp16 padded feat lo

typedef _Float16 half8 __attribute__((ext_vector_type(8)));
typedef float f32x4 __attribute__((ext_vector_type(4)));

__device__ __forceinline__ void gload16(const void* g, void* l) {
    __builtin_amdgcn_global_load_lds((const __attribute__((address_space(1))) void*)g,
                                     (__attribute__((address_space(3))) void*)l, 16, 0, 0);
}

// fp32 (2394,512) channel-last transpose of net (512,2394), via LDS 32x32 tiles
__global__ __launch_bounds__(256) void k_transpose_feat(const float* __restrict__ in,
                                                        float* __restrict__ featT) {
    __shared__ float tl[32][33];
    int tx = threadIdx.x & 31, tg = threadIdx.x >> 5;     // 32 x 8
    int posBase = blockIdx.x * 32, ciBase = blockIdx.y * 32;
#pragma unroll
    for (int j = 0; j < 4; ++j) {
        int ci = ciBase + tg + j * 8;
        int pos = posBase + tx;
        tl[tg + j * 8][tx] = (pos < NPOS) ? in[(size_t)ci * NPOS + pos] : 0.f;
    }
    __syncthreads();
#pragma unroll
    for (int j = 0; j < 4; ++j) {
        int pos = posBase + tg + j * 8;
        int ci = ciBase + tx;
        if (pos < NPOS) featT[(size_t)pos * 512 + ci] = tl[tx][tg + j * 8];
    }
}

// featT fp32 -> padded fp16 hi/lo planes [41][65][512], scaled by 16 (exact pow2)
__global__ void k_pad_split(const float* __restrict__ featT,
                            _Float16* __restrict__ FPH, _Float16* __restrict__ FPL) {
    int idx = blockIdx.x * 256 + threadIdx.x;   // 41*65*512 = 1,364,480 exact
    int ci = idx & 511;
    int rc = idx >> 9;            // hp*65 + wp
    int hp = rc / 65, wp = rc - hp * 65;
    int h = hp - 1, w = wp - 1;
    float a = 0.f;
    if ((unsigned)h < 38u && (unsigned)w < 63u)
        a = featT[(size_t)(h * 63 + w) * 512 + ci] * 16.f;
    _Float16 ah = (_Float16)a;
    _Float16 al = (_Float16)(a - (float)ah);
    FPH[idx] = ah; FPL[idx] = al;
}

// w_rpn (co,ci,3,3) -> fp16 hi/lo planes [co][k = p*512+ci], scaled by 128 (exact pow2)
__global__ void k_prep_wf16(const float* __restrict__ w,
                            _Float16* __restrict__ BH, _Float16* __restrict__ BL) {
    int idx = blockIdx.x * 256 + threadIdx.x;   // 512*4608 = 2,359,296 exact
    int co = idx / KK;
    int rem = idx - co * KK;
    int p = rem >> 9;
    int ci = rem & 511;
    float b = w[(co * CIN + ci) * 9 + p] * 128.f;
    _Float16 bh = (_Float16)b;
    _Float16 bl = (_Float16)(b - (float)bh);
    BH[idx] = bh; BL[idx] = bl;
}

// 3x3 SAME conv as implicit-im2col split-fp16 MFMA GEMM.
// C = [(AH+AL)(BH+BL)]/2048, keeping AH*BH + AH*BL + AL*BH (error ~2^-22/product).
// Tile: 128 pos x 64 co, BK=64, 4 waves (each 64x32 out), split-K=2 -> P0/P1.
// LDS 48KB: A planes [128][64]f16 hi/lo (32KB) + B planes [64][64]f16 hi/lo (16KB).
// XOR swizzle: kgroup ^= (row&7); gload_lds writes linearly so the source address
// carries the inverse (= same) permutation; ds_read applies it on the read side.
__global__ __launch_bounds__(256, 3) void k_conv3_mfma(
    const _Float16* __restrict__ FPH, const _Float16* __restrict__ FPL,
    const _Float16* __restrict__ BHp, const _Float16* __restrict__ BLp,
    float* __restrict__ P0, float* __restrict__ P1)
{
    __shared__ __align__(16) char lds[49152];
    const int t = threadIdx.x;
    const int wave = t >> 6, lane = t & 63;
    const int posBase = blockIdx.x * 128;
    const int coBase  = blockIdx.y * 64;
    const int z = blockIdx.z;
    float* __restrict__ P = z ? P1 : P0;
    const int wm = wave >> 1, wn = wave & 1;
    const int lr = lane & 15, lg = lane >> 4;

    // fragment ds_read byte addresses (swizzled), fixed across k-loop
    int addrA[4][2], addrB[2][2];
#pragma unroll
    for (int m = 0; m < 4; ++m) {
        int row = wm * 64 + m * 16 + lr;
        int x = row & 7;
        addrA[m][0] = row * 128 + ((lg ^ x) << 4);
        addrA[m][1] = row * 128 + (((4 + lg) ^ x) << 4);
    }
#pragma unroll
    for (int n = 0; n < 2; ++n) {
        int row = wn * 32 + n * 16 + lr;
        int x = row & 7;
        addrB[n][0] = 32768 + row * 128 + ((lg ^ x) << 4);
        addrB[n][1] = 32768 + row * 128 + (((4 + lg) ^ x) << 4);
    }

    // staging: per-lane source bases (pre-swizzled) + linear LDS dests
    int baseA[4], ldsAo[4];
#pragma unroll
    for (int s = 0; s < 4; ++s) {
        int row = (wave * 4 + s) * 8 + (lane >> 3);
        int pos = posBase + row;
        int h = pos / 63;
        int w = pos - h * 63;
        int swz = ((lane & 7) ^ (row & 7)) * 8;     // f16 units
        baseA[s] = (h * 65 + w) * 512 + swz;        // into padded plane
        ldsAo[s] = (wave * 4 + s) * 1024 + lane * 16;
    }
    int baseB[2], ldsBo[2];
#pragma unroll
    for (int s = 0; s < 2; ++s) {
        int row = (wave * 2 + s) * 8 + (lane >> 3);
        int swz = ((lane & 7) ^ (row & 7)) * 8;
        baseB[s] = (coBase + row) * KK + swz;
        ldsBo[s] = 32768 + (wave * 2 + s) * 1024 + lane * 16;
    }

    f32x4 acc[4][2];
#pragma unroll
    for (int m = 0; m < 4; ++m)
#pragma unroll
        for (int n = 0; n < 2; ++n) acc[m][n] = (f32x4){0.f, 0.f, 0.f, 0.f};

    const int kbeg = z * 2304;
    for (int step = 0; step < 36; ++step) {
        int k0 = kbeg + step * 64;
        int p = k0 >> 9;                 // tap 0..8 (chunks never straddle a tap)
        int ci0 = k0 & 511;
        int kh = p / 3;
        int kw = p - kh * 3;
        int dA = (kh * 65 + kw) * 512 + ci0;
#pragma unroll
        for (int s = 0; s < 4; ++s) {
            int so = baseA[s] + dA;
            gload16(FPH + so, lds + ldsAo[s]);
            gload16(FPL + so, lds + 16384 + ldsAo[s]);
        }
#pragma unroll
        for (int s = 0; s < 2; ++s) {
            int so = baseB[s] + k0;
            gload16(BHp + so, lds + ldsBo[s]);
            gload16(BLp + so, lds + 8192 + ldsBo[s]);
        }
        __syncthreads();   // drains vmcnt -> LDS tiles ready
#pragma unroll
        for (int ks = 0; ks < 2; ++ks) {
            half8 aH[4], aL[4], bH[2], bL[2];
#pragma unroll
            for (int m = 0; m < 4; ++m) {
                aH[m] = *(const half8*)(lds + addrA[m][ks]);
                aL[m] = *(const half8*)(lds + 16384 + addrA[m][ks]);
            }
#pragma unroll
            for (int n = 0; n < 2; ++n) {
                bH[n] = *(const half8*)(lds + addrB[n][ks]);
                bL[n] = *(const half8*)(lds + 8192 + addrB[n][ks]);
            }
#pragma unroll
            for (int m = 0; m < 4; ++m)
#pragma unroll
                for (int n = 0; n < 2; ++n) {
                    acc[m][n] = __builtin_amdgcn_mfma_f32_16x16x32_f16(aH[m], bH[n], acc[m][n], 0, 0, 0);
                    acc[m][n] = __builtin_amdgcn_mfma_f32_16x16x32_f16(aH[m], bL[n], acc[m][n], 0, 0, 0);
                    acc[m][n] = __builtin_amdgcn_mfma_f32_16x16x32_f16(aL[m], bH[n], acc[m][n], 0, 0, 0);
                }
        }
        __syncthreads();   // protect LDS before next-step staging
    }

    // epilogue: D[row][col]: col = lane&15, row = (lane>>4)*4 + r ; scale 1/2048
#pragma unroll
    for (int m = 0; m < 4; ++m) {
        int pbase = posBase + wm * 64 + m * 16 + lg * 4;
        int co = coBase + wn * 32 + lr;
#pragma unroll
        for (int r = 0; r < 4; ++r) {
            int pos = pbase + r;
            if (pos < NPOS) {
                P[(size_t)pos * 512 + co]      = acc[m][0][r] * (1.f / 2048.f);
                P[(size_t)pos * 512 + co + 16] = acc[m][1][r] * (1.f / 2048.f);
            }
        }
    }
}

// 1x1 heads (fuses conv bias+ReLU over P0+P1) + softmax-prob + decode + clip + key.
__global__ __launch_bounds__(256) void k_heads(const float* __restrict__ P0,
                                               const float* __restrict__ P1,
                                               const float* __restrict__ brpn,
                                               const float* __restrict__ wcls,
                                               const float* __restrict__ bcls,
                                               const float* __restrict__ wbbox,
                                               const float* __restrict__ bbbox,
                                               const float* __restrict__ anchors,
                                               float* __restrict__ proposals,
                                               unsigned long long* __restrict__ keys) {
    __shared__ float x[512];
    __shared__ float part[54][4];
    __shared__ float logit[54];
    int pos = blockIdx.x;
    int t = threadIdx.x;
    {
        float v0 = P0[(size_t)pos * 512 + t] + P1[(size_t)pos * 512 + t] + brpn[t];
        float v1 = P0[(size_t)pos * 512 + t + 256] + P1[(size_t)pos * 512 + t + 256] + brpn[t + 256];
        x[t] = v0 > 0.f ? v0 : 0.f;
        x[t + 256] = v1 > 0.f ? v1 : 0.f;
    }
    __syncthreads();
    if (t < 216) {
        int o = t >> 2, q = t & 3;
        const float* wr = (o < 18) ? (wcls + o * 512) : (wbbox + (o - 18) * 512);
        float s = 0.f;
        int base = q * 128;
#pragma unroll 4
        for (int k2 = 0; k2 < 128; ++k2) s += x[base + k2] * wr[base + k2];
        part[o][q] = s;
    }
    __syncthreads();
    if (t < 54) {
        float b = (t < 18) ? bcls[t] : bbbox[t - 18];
        logit[t] = part[t][0] + part[t][1] + part[t][2] + part[t][3] + b;
    }
    __syncthreads();
    if (t < 9) {
        int a = t;
        float bg = logit[a], fg = logit[9 + a];
        float score = 1.f / (1.f + expf(bg - fg));
        float dx = logit[18 + 4 * a], dy = logit[19 + 4 * a];
        float dw = logit[20 + 4 * a], dh = logit[21 + 4 * a];
        int idx = pos * 9 + a;
        float ax1 = anchors[idx * 4 + 0], ay1 = anchors[idx * 4 + 1];
        float ax2 = anchors[idx * 4 + 2], ay2 = anchors[idx * 4 + 3];
        float aw = ax2 - ax1 + 1.f, ah = ay2 - ay1 + 1.f;
        float cx = ax1 + 0.5f * aw, cy = ay1 + 0.5f * ah;
        float pcx = dx * aw + cx, pcy = dy * ah + cy;
        float pw = expf(dw) * aw, ph = expf(dh) * ah;
        float x1 = fminf(fmaxf(pcx - 0.5f * pw, 0.f), 999.f);
        float y1 = fminf(fmaxf(pcy - 0.5f * ph, 0.f), 599.f);
        float x2 = fminf(fmaxf(pcx + 0.5f * pw, 0.f), 999.f);
        float y2 = fminf(fmaxf(pcy + 0.5f * ph, 0.f), 599.f);
        proposals[idx * 4 + 0] = x1; proposals[idx * 4 + 1] = y1;
        proposals[idx * 4 + 2] = x2; proposals[idx * 4 + 3] = y2;
        union { float f; unsigned int i; } sv; sv.f = score;
        keys[idx] = (((unsigned long long)sv.i) << 32) |
                    (unsigned long long)(0xFFFFFFFFu - (unsigned)idx);
    }
}

__global__ __launch_bounds__(256) void k_rank_partial(const unsigned long long* __restrict__ keys,
                                                      unsigned int* __restrict__ rpart) {
    __shared__ unsigned long long kc[1024];
    int i = blockIdx.x * 256 + threadIdx.x;
    int q = blockIdx.y;
    unsigned long long myk = (i < NANCH) ? keys[i] : 0xFFFFFFFFFFFFFFFFull;
    int j0 = q * QLEN;
    int j1 = j0 + QLEN; if (j1 > NANCH) j1 = NANCH;
    unsigned int cnt = 0;
    for (int base = j0; base < j1; base += 1024) {
        int nload = j1 - base; if (nload > 1024) nload = 1024;
        __syncthreads();
        for (int u = threadIdx.x; u < 1024; u += 256)
            kc[u] = (base + u < j1) ? keys[base + u] : 0ull;
        __syncthreads();
        for (int u = 0; u < nload; ++u)
            cnt += (kc[u] > myk) ? 1u : 0u;
    }
    if (i < NANCH) rpart[i * NQ + q] = cnt;
}

__global__ void k_zero_sboxes(float* __restrict__ sboxes) {
    int i = blockIdx.x * 256 + threadIdx.x;
    if (i < PRE * 4) sboxes[i] = 0.f;
}

__global__ void k_rank_scatter(const unsigned int* __restrict__ rpart,
                               const float* __restrict__ proposals,
                               float* __restrict__ sboxes) {
    int i = blockIdx.x * 256 + threadIdx.x;
    if (i >= NANCH) return;
    unsigned int r = 0;
#pragma unroll
    for (int q = 0; q < NQ; q++) r += rpart[i * NQ + q];
    if (r < PRE) {
        sboxes[r * 4 + 0] = proposals[i * 4 + 0];
        sboxes[r * 4 + 1] = proposals[i * 4 + 1];
        sboxes[r * 4 + 2] = proposals[i * 4 + 2];
        sboxes[r * 4 + 3] = proposals[i * 4 + 3];
    }
}

__global__ __launch_bounds__(64) void k_nms_mask(const float* __restrict__ sboxes,
                                                 unsigned long long* __restrict__ mask) {
    __shared__ float bx[64][4];
    int ib = blockIdx.x, jb = blockIdx.y;
    int lane = threadIdx.x;
    int j = jb * 64 + lane;
    if (j < PRE) {
        bx[lane][0] = sboxes[j * 4 + 0]; bx[lane][1] = sboxes[j * 4 + 1];
        bx[lane][2] = sboxes[j * 4 + 2]; bx[lane][3] = sboxes[j * 4 + 3];
    } else {
        bx[lane][0] = 3e8f; bx[lane][1] = 3e8f; bx[lane][2] = 3e8f; bx[lane][3] = 3e8f;
    }
    __syncthreads();
    int i = ib * 64 + lane;
    if (i >= PRE) return;
    float x1 = sboxes[i * 4 + 0], y1 = sboxes[i * 4 + 1];
    float x2 = sboxes[i * 4 + 2], y2 = sboxes[i * 4 + 3];
    float ar = (x2 - x1 + 1.f) * (y2 - y1 + 1.f);
    unsigned long long bits = 0;
#pragma unroll 4
    for (int u = 0; u < 64; u++) {
        int j2 = jb * 64 + u;
        float iw = fminf(x2, bx[u][2]) - fmaxf(x1, bx[u][0]) + 1.f;
        float ih = fminf(y2, bx[u][3]) - fmaxf(y1, bx[u][1]) + 1.f;
        iw = fmaxf(iw, 0.f); ih = fmaxf(ih, 0.f);
        float inter = iw * ih;
        float arj = (bx[u][2] - bx[u][0] + 1.f) * (bx[u][3] - bx[u][1] + 1.f);
        float iou = inter / (ar + arj - inter);
        if (iou > 0.7f && j2 > i) bits |= (1ull << u);
    }
    mask[(size_t)i * NWORD + jb] = bits;
}

// greedy scan: word-block iteration (one broadcast per 64-block + one row-load per kept)
__global__ __launch_bounds__(64) void k_nms_scan(const unsigned long long* __restrict__ mask,
                                                 int* __restrict__ keep) {
    int lane = threadIdx.x;
    unsigned long long rem0 = 0, rem1 = 0;
    int nk = 0;
    for (int b = 0; b < NWORD && nk < POST; ++b) {
        unsigned long long rm = (b < 64) ? __shfl(rem0, b) : __shfl(rem1, b - 64);
        unsigned long long valid = (b == NWORD - 1) ? ((1ull << 48) - 1) : ~0ull;
        unsigned long long alive = ~rm & valid;
        while (alive) {
            int u = __ffsll((long long)alive) - 1;
            int i = b * 64 + u;
            if (lane == 0) keep[nk] = i;
            ++nk;
            if (nk == POST) break;
            const unsigned long long* row = mask + (size_t)i * NWORD;
            rem0 |= row[lane];
            if (lane < NWORD - 64) rem1 |= row[64 + lane];
            unsigned long long rmb = (b < 64) ? __shfl(rem0, b) : __shfl(rem1, b - 64);
            unsigned long long above = (u == 63) ? 0ull : (~0ull << (u + 1));
            alive = ~rmb & valid & above;
        }
    }
    for (int k2 = nk + lane; k2 < POST; k2 += 64) keep[k2] = PRE - 1;
}

// headers: roi box at the start of each of the roi's 8 output chunks
__global__ __launch_bounds__(256) void k_gather_rois(const float* sboxes, const int* keep,
                                                     float* outF) {
    int t = threadIdx.x;
    float4 box[2];
    int nr = 0;
    for (int r = t; r < POST; r += 256) {
        int ki = keep[r];
        if (ki < 0) ki = 0; if (ki > PRE - 1) ki = PRE - 1;
        box[nr++] = *reinterpret_cast<const float4*>(sboxes + ki * 4);
    }
    __syncthreads();
    nr = 0;
    for (int r = t; r < POST; r += 256) {
        float4 b = box[nr++];
#pragma unroll
        for (int cg = 0; cg < 8; ++cg)
            *reinterpret_cast<float4*>(outF + (size_t)(r * 512 + cg * 64) * 49) = b;
    }
}

// FAST crop: coalesced featT reads (lane=channel) + LDS-staged coalesced writes.
// grid (POST, 2), block 256 = 4 waves; wave w handles cg = blockIdx.y*4+w.
__global__ __launch_bounds__(256) void k_crop_fast(const float* __restrict__ featT,
                                                   float* out) {
    __shared__ float lds[4][49 * 65];   // [wave][e*65 + c_local], padded vs bank conflicts
    int r = blockIdx.x;
    int w = threadIdx.x >> 6, lane = threadIdx.x & 63;
    int cg = blockIdx.y * 4 + w;
    int c = cg * 64 + lane;
    float* chunk = out + (size_t)(r * 512 + cg * 64) * 49;
    const float4 b = *reinterpret_cast<const float4*>(chunk);   // wave-uniform broadcast
    float x1 = b.x, y1 = b.y, x2 = b.z, y2 = b.w;
    float by1 = (y1 / 16.f) / 37.f, bx1 = (x1 / 16.f) / 62.f;
    float by2 = (y2 / 16.f) / 37.f, bx2 = (x2 / 16.f) / 62.f;
    float dyn = by2 - by1, dxn = bx2 - bx1;
    for (int e = 0; e < 49; ++e) {
        int oy = e / 7, ox = e - oy * 7;
        float vv[4];
#pragma unroll
        for (int dy = 0; dy < 2; ++dy) {
            int sy = 2 * oy + dy;
            float ty = (float)sy / 13.f;
            float ys = by1 * 37.f + (ty * dyn) * 37.f;
            float yf = floorf(ys);
            float wy = ys - yf;
            int y0  = (int)fminf(fmaxf(yf, 0.f), 37.f);
            int y1i = (int)fminf(fmaxf(yf + 1.f, 0.f), 37.f);
#pragma unroll
            for (int dxx = 0; dxx < 2; ++dxx) {
                int sx = 2 * ox + dxx;
                float tx = (float)sx / 13.f;
                float xs = bx1 * 62.f + (tx * dxn) * 62.f;
                float xf = floorf(xs);
                float wx = xs - xf;
                int x0  = (int)fminf(fmaxf(xf, 0.f), 62.f);
                int x1i = (int)fminf(fmaxf(xf + 1.f, 0.f), 62.f);
                float f00 = featT[(size_t)(y0 * 63 + x0) * 512 + c];
                float f01 = featT[(size_t)(y0 * 63 + x1i) * 512 + c];
                float f10 = featT[(size_t)(y1i * 63 + x0) * 512 + c];
                float f11 = featT[(size_t)(y1i * 63 + x1i) * 512 + c];
                vv[dy * 2 + dxx] = f00 * (1.f - wy) * (1.f - wx) + f01 * (1.f - wy) * wx +
                                   f10 * wy * (1.f - wx) + f11 * wy * wx;
            }
        }
        lds[w][e * 65 + lane] = fmaxf(fmaxf(vv[0], vv[1]), fmaxf(vv[2], vv[3]));
    }
    __syncthreads();
    // linear coalesced write of the wave's 64x49 chunk
    for (int i = lane; i < 64 * 49; i += 64) {
        int cl = i / 49, e = i - cl * 49;
        chunk[i] = lds[w][e * 65 + cl];
    }
}

// SLOW fallback crop (reads NCHW net) — used only if ws too small
__global__ __launch_bounds__(64) void k_crop_slow(const float* __restrict__ net,
                                                  float* out) {
    int r = blockIdx.x, cg = blockIdx.y;
    int lane = threadIdx.x;
    int c = cg * 64 + lane;
    const float4 b = *reinterpret_cast<const float4*>(out + (size_t)(r * 512 + cg * 64) * 49);
    float x1 = b.x, y1 = b.y, x2 = b.z, y2 = b.w;
    float by1 = (y1 / 16.f) / 37.f, bx1 = (x1 / 16.f) / 62.f;
    float by2 = (y2 / 16.f) / 37.f, bx2 = (x2 / 16.f) / 62.f;
    float dyn = by2 - by1, dxn = bx2 - bx1;
    const float* fc = net + (size_t)c * NPOS;
    float* orow = out + ((size_t)r * 512 + c) * 49;
    for (int e = 0; e < 49; ++e) {
        int oy = e / 7, ox = e - oy * 7;
        float vv[4];
#pragma unroll
        for (int dy = 0; dy < 2; ++dy) {
            int sy = 2 * oy + dy;
            float ty = (float)sy / 13.f;
            float ys = by1 * 37.f + (ty * dyn) * 37.f;
            float yf = floorf(ys);
            float wy = ys - yf;
            int y0  = (int)fminf(fmaxf(yf, 0.f), 37.f);
            int y1i = (int)fminf(fmaxf(yf + 1.f, 0.f), 37.f);
#pragma unroll
            for (int dxx = 0; dxx < 2; ++dxx) {
                int sx = 2 * ox + dxx;
                float tx = (float)sx / 13.f;
                float xs = bx1 * 62.f + (tx * dxn) * 62.f;
                float xf = floorf(xs);
                float wx = xs - xf;
                int x0  = (int)fminf(fmaxf(xf, 0.f), 62.f);
                int x1i = (int)fminf(fmaxf(xf + 1.f, 0.f), 62.f);
                float f00 = fc[y0 * 63 + x0];
                float f01 = fc[y0 * 63 + x1i];
                float f10 = fc[y1i * 63 + x0];
                float f11 = fc[y1i * 63 + x1i];
                vv[dy * 2 + dxx] = f00 * (1.f - wy) * (1.f - wx) + f01 * (1.f - wy) * wx +
                                   f10 * wy * (1.f - wx) + f11 * wy * wx;
            }
        }
        orow[e] = fmaxf(fmaxf(vv[0], vv[1]), fmaxf(vv[2], vv[3]));
    }
}

extern "C" void kernel_launch(void* const* d_in, const int* in_sizes, int n_in,
                              void* d_out, int out_size, void* d_ws, size_t ws_size,
                              hipStream_t stream) {
    auto find = [&](int count, int fallback) {
        for (int i = 0; i < n_in; ++i) if (in_sizes[i] == count) return i;
        return fallback;
    };
    const float* net   = (const float*)d_in[find(NPOS * CIN, 0)];
    const float* wrpn  = (const float*)d_in[find(512 * KK, 1)];
    const float* brpn  = (const float*)d_in[find(512, 2)];
    const float* wcls  = (const float*)d_in[find(18 * 512, 3)];
    const float* bcls  = (const float*)d_in[find(18, 4)];
    const float* wbbox = (const float*)d_in[find(36 * 512, 5)];
    const float* bbbox = (const float*)d_in[find(36, 6)];
    const float* anch  = (const float*)d_in[find(NANCH * 4, 7)];

    char* ob = (char*)d_out;
    _Float16* BH             = (_Float16*)(ob + OFF_BH);
    _Float16* BL             = (_Float16*)(ob + OFF_BL);
    unsigned long long* mask = (unsigned long long*)(ob + OFF_BH);   // aliases dead BH/BL
    float* P0                = (float*)(ob + OFF_P0);
    float* P1                = (float*)(ob + OFF_P1);
    float* sboxes            = (float*)(ob + OFF_SBOX);
    int* keep                = (int*)(ob + OFF_KEEP);
    unsigned long long* keys = (unsigned long long*)(ob + OFF_KEYS);
    float* proposals         = (float*)(ob + OFF_PROP);
    unsigned int* rpart      = (unsigned int*)(ob + OFF_RPART);
    _Float16* FPH            = (_Float16*)(ob + OFF_FPH);
    _Float16* FPL            = (_Float16*)(ob + OFF_FPL);
    float* outF              = (float*)d_out;

    // featT in d_ws if it fits (survives the output-overwriting crop -> fast path).
    // Fallback: alias dead-until-conv P0 region (pad_split consumes featT before conv).
    const bool ws_ok = (ws_size >= (size_t)FEATT_BYTES);
    float* featT = ws_ok ? (float*)d_ws : (float*)(ob + OFF_P0);

    hipLaunchKernelGGL(k_transpose_feat, dim3(75, 16), dim3(256), 0, stream, net, featT);
    hipLaunchKernelGGL(k_pad_split, dim3(5330), dim3(256), 0, stream, featT, FPH, FPL);
    hipLaunchKernelGGL(k_prep_wf16, dim3(9216), dim3(256), 0, stream, wrpn, BH, BL);
    hipLaunchKernelGGL(k_conv3_mfma, dim3(19, 8, 2), dim3(256), 0, stream, FPH, FPL, BH, BL, P0, P1);
    hipLaunchKernelGGL(k_heads, dim3(NPOS), dim3(256), 0, stream, P0, P1, brpn, wcls, bcls, wbbox, bbbox, anch, proposals, keys);
    hipLaunchKernelGGL(k_rank_partial, dim3(85, NQ), dim3(256), 0, stream, keys, rpart);
    hipLaunchKernelGGL(k_zero_sboxes, dim3((PRE * 4 + 255) / 256), dim3(256), 0, stream, sboxes);
    hipLaunchKernelGGL(k_rank_scatter, dim3(85), dim3(256), 0, stream, rpart, proposals, sboxes);
    hipLaunchKernelGGL(k_nms_mask, dim3(NWORD, NWORD), dim3(64), 0, stream, sboxes, mask);
    hipLaunchKernelGGL(k_nms_scan, dim3(1), dim3(64), 0, stream, mask, keep);
    hipLaunchKernelGGL(k_gather_rois, dim3(1), dim3(256), 0, stream, sboxes, keep, outF);
    if (ws_ok)
        hipLaunchKernelGGL(k_crop_fast, dim3(POST, 2), dim3(256), 0, stream, featT, outF);
    else
        hipLaunchKernelGGL(k_crop_slow, dim3(POST, 8), dim3(64), 0, stream, net, outF);
}

// Round 2
// 426.835 us; speedup vs baseline: 1.4542x; 1.0922x over previous
//
#include <hip/hip_runtime.h>
#include <stdint.h>

// Problem constants (fp32 everywhere)
#define NPOS 2394          // 38*63
#define CIN 512
#define KK 4608            // 512*9
#define NANCH 21546        // NPOS*9
#define PRE 6000
#define POST 300
#define NWORD 94           // ceil(6000/64)
#define NQ 8
#define QLEN 2694          // ceil(21546/8)
#define FEATT_BYTES 4902912   // NPOS*512*4

// ---- d_out scratch map (bytes). out bytes = 30,105,600.
#define OFF_BH    0                  // fp16 weight hi plane  [512][4608] = 4,718,592
#define OFF_BL    4718592            // fp16 weight lo plane
#define OFF_P0    9437184
#define OFF_SBOX  9437184            // aliases dead P0
#define OFF_KEEP  9533440
#define OFF_P1    14340096
#define OFF_KEYS  19243008
#define OFF_PROP  19415552
#define OFF_RPART 19760384
#define OFF_FPH   20450048           // fp16 padded feat hi [41][65][512] = 2,728,960
#define OFF_FPL   23179264           // fp16 padded feat lo

typedef _Float16 half8 __attribute__((ext_vector_type(8)));
typedef float f32x4 __attribute__((ext_vector_type(4)));

__device__ __forceinline__ void gload16(const void* g, void* l) {
    __builtin_amdgcn_global_load_lds((const __attribute__((address_space(1))) void*)g,
                                     (__attribute__((address_space(3))) void*)l, 16, 0, 0);
}

// fp32 (2394,512) channel-last transpose of net (512,2394), via LDS 32x32 tiles
__global__ __launch_bounds__(256) void k_transpose_feat(const float* __restrict__ in,
                                                        float* __restrict__ featT) {
    __shared__ float tl[32][33];
    int tx = threadIdx.x & 31, tg = threadIdx.x >> 5;     // 32 x 8
    int posBase = blockIdx.x * 32, ciBase = blockIdx.y * 32;
#pragma unroll
    for (int j = 0; j < 4; ++j) {
        int ci = ciBase + tg + j * 8;
        int pos = posBase + tx;
        tl[tg + j * 8][tx] = (pos < NPOS) ? in[(size_t)ci * NPOS + pos] : 0.f;
    }
    __syncthreads();
#pragma unroll
    for (int j = 0; j < 4; ++j) {
        int pos = posBase + tg + j * 8;
        int ci = ciBase + tx;
        if (pos < NPOS) featT[(size_t)pos * 512 + ci] = tl[tx][tg + j * 8];
    }
}

// featT fp32 -> padded fp16 hi/lo planes [41][65][512], scaled by 16 (exact pow2)
__global__ void k_pad_split(const float* __restrict__ featT,
                            _Float16* __restrict__ FPH, _Float16* __restrict__ FPL) {
    int idx = blockIdx.x * 256 + threadIdx.x;   // 41*65*512 = 1,364,480 exact
    int ci = idx & 511;
    int rc = idx >> 9;            // hp*65 + wp
    int hp = rc / 65, wp = rc - hp * 65;
    int h = hp - 1, w = wp - 1;
    float a = 0.f;
    if ((unsigned)h < 38u && (unsigned)w < 63u)
        a = featT[(size_t)(h * 63 + w) * 512 + ci] * 16.f;
    _Float16 ah = (_Float16)a;
    _Float16 al = (_Float16)(a - (float)ah);
    FPH[idx] = ah; FPL[idx] = al;
}

// w_rpn (co,ci,3,3) -> fp16 hi/lo planes [co][k = p*512+ci], scaled by 128 (exact pow2)
__global__ void k_prep_wf16(const float* __restrict__ w,
                            _Float16* __restrict__ BH, _Float16* __restrict__ BL) {
    int idx = blockIdx.x * 256 + threadIdx.x;   // 512*4608 = 2,359,296 exact
    int co = idx / KK;
    int rem = idx - co * KK;
    int p = rem >> 9;
    int ci = rem & 511;
    float b = w[(co * CIN + ci) * 9 + p] * 128.f;
    _Float16 bh = (_Float16)b;
    _Float16 bl = (_Float16)(b - (float)bh);
    BH[idx] = bh; BL[idx] = bl;
}

// 3x3 SAME conv as implicit-im2col split-fp16 MFMA GEMM.
// C = [(AH+AL)(BH+BL)]/2048, keeping AH*BH + AH*BL + AL*BH (error ~2^-22/product).
// Tile: 128 pos x 64 co, BK=64, 4 waves (each 64x32 out), split-K=2 -> P0/P1.
__global__ __launch_bounds__(256, 3) void k_conv3_mfma(
    const _Float16* __restrict__ FPH, const _Float16* __restrict__ FPL,
    const _Float16* __restrict__ BHp, const _Float16* __restrict__ BLp,
    float* __restrict__ P0, float* __restrict__ P1)
{
    __shared__ __align__(16) char lds[49152];
    const int t = threadIdx.x;
    const int wave = t >> 6, lane = t & 63;
    const int posBase = blockIdx.x * 128;
    const int coBase  = blockIdx.y * 64;
    const int z = blockIdx.z;
    float* __restrict__ P = z ? P1 : P0;
    const int wm = wave >> 1, wn = wave & 1;
    const int lr = lane & 15, lg = lane >> 4;

    // fragment ds_read byte addresses (swizzled), fixed across k-loop
    int addrA[4][2], addrB[2][2];
#pragma unroll
    for (int m = 0; m < 4; ++m) {
        int row = wm * 64 + m * 16 + lr;
        int x = row & 7;
        addrA[m][0] = row * 128 + ((lg ^ x) << 4);
        addrA[m][1] = row * 128 + (((4 + lg) ^ x) << 4);
    }
#pragma unroll
    for (int n = 0; n < 2; ++n) {
        int row = wn * 32 + n * 16 + lr;
        int x = row & 7;
        addrB[n][0] = 32768 + row * 128 + ((lg ^ x) << 4);
        addrB[n][1] = 32768 + row * 128 + (((4 + lg) ^ x) << 4);
    }

    // staging: per-lane source bases (pre-swizzled) + linear LDS dests
    int baseA[4], ldsAo[4];
#pragma unroll
    for (int s = 0; s < 4; ++s) {
        int row = (wave * 4 + s) * 8 + (lane >> 3);
        int pos = posBase + row;
        int h = pos / 63;
        int w = pos - h * 63;
        int swz = ((lane & 7) ^ (row & 7)) * 8;     // f16 units
        baseA[s] = (h * 65 + w) * 512 + swz;        // into padded plane
        ldsAo[s] = (wave * 4 + s) * 1024 + lane * 16;
    }
    int baseB[2], ldsBo[2];
#pragma unroll
    for (int s = 0; s < 2; ++s) {
        int row = (wave * 2 + s) * 8 + (lane >> 3);
        int swz = ((lane & 7) ^ (row & 7)) * 8;
        baseB[s] = (coBase + row) * KK + swz;
        ldsBo[s] = 32768 + (wave * 2 + s) * 1024 + lane * 16;
    }

    f32x4 acc[4][2];
#pragma unroll
    for (int m = 0; m < 4; ++m)
#pragma unroll
        for (int n = 0; n < 2; ++n) acc[m][n] = (f32x4){0.f, 0.f, 0.f, 0.f};

    const int kbeg = z * 2304;
    for (int step = 0; step < 36; ++step) {
        int k0 = kbeg + step * 64;
        int p = k0 >> 9;                 // tap 0..8 (chunks never straddle a tap)
        int ci0 = k0 & 511;
        int kh = p / 3;
        int kw = p - kh * 3;
        int dA = (kh * 65 + kw) * 512 + ci0;
#pragma unroll
        for (int s = 0; s < 4; ++s) {
            int so = baseA[s] + dA;
            gload16(FPH + so, lds + ldsAo[s]);
            gload16(FPL + so, lds + 16384 + ldsAo[s]);
        }
#pragma unroll
        for (int s = 0; s < 2; ++s) {
            int so = baseB[s] + k0;
            gload16(BHp + so, lds + ldsBo[s]);
            gload16(BLp + so, lds + 8192 + ldsBo[s]);
        }
        __syncthreads();   // drains vmcnt -> LDS tiles ready
#pragma unroll
        for (int ks = 0; ks < 2; ++ks) {
            half8 aH[4], aL[4], bH[2], bL[2];
#pragma unroll
            for (int m = 0; m < 4; ++m) {
                aH[m] = *(const half8*)(lds + addrA[m][ks]);
                aL[m] = *(const half8*)(lds + 16384 + addrA[m][ks]);
            }
#pragma unroll
            for (int n = 0; n < 2; ++n) {
                bH[n] = *(const half8*)(lds + addrB[n][ks]);
                bL[n] = *(const half8*)(lds + 8192 + addrB[n][ks]);
            }
#pragma unroll
            for (int m = 0; m < 4; ++m)
#pragma unroll
                for (int n = 0; n < 2; ++n) {
                    acc[m][n] = __builtin_amdgcn_mfma_f32_16x16x32_f16(aH[m], bH[n], acc[m][n], 0, 0, 0);
                    acc[m][n] = __builtin_amdgcn_mfma_f32_16x16x32_f16(aH[m], bL[n], acc[m][n], 0, 0, 0);
                    acc[m][n] = __builtin_amdgcn_mfma_f32_16x16x32_f16(aL[m], bH[n], acc[m][n], 0, 0, 0);
                }
        }
        __syncthreads();   // protect LDS before next-step staging
    }

    // epilogue: D[row][col]: col = lane&15, row = (lane>>4)*4 + r ; scale 1/2048
#pragma unroll
    for (int m = 0; m < 4; ++m) {
        int pbase = posBase + wm * 64 + m * 16 + lg * 4;
        int co = coBase + wn * 32 + lr;
#pragma unroll
        for (int r = 0; r < 4; ++r) {
            int pos = pbase + r;
            if (pos < NPOS) {
                P[(size_t)pos * 512 + co]      = acc[m][0][r] * (1.f / 2048.f);
                P[(size_t)pos * 512 + co + 16] = acc[m][1][r] * (1.f / 2048.f);
            }
        }
    }
}

// 1x1 heads (fuses conv bias+ReLU over P0+P1) + softmax-prob + decode + clip + key.
__global__ __launch_bounds__(256) void k_heads(const float* __restrict__ P0,
                                               const float* __restrict__ P1,
                                               const float* __restrict__ brpn,
                                               const float* __restrict__ wcls,
                                               const float* __restrict__ bcls,
                                               const float* __restrict__ wbbox,
                                               const float* __restrict__ bbbox,
                                               const float* __restrict__ anchors,
                                               float* __restrict__ proposals,
                                               unsigned long long* __restrict__ keys) {
    __shared__ float x[512];
    __shared__ float part[54][4];
    __shared__ float logit[54];
    int pos = blockIdx.x;
    int t = threadIdx.x;
    {
        float v0 = P0[(size_t)pos * 512 + t] + P1[(size_t)pos * 512 + t] + brpn[t];
        float v1 = P0[(size_t)pos * 512 + t + 256] + P1[(size_t)pos * 512 + t + 256] + brpn[t + 256];
        x[t] = v0 > 0.f ? v0 : 0.f;
        x[t + 256] = v1 > 0.f ? v1 : 0.f;
    }
    __syncthreads();
    if (t < 216) {
        int o = t >> 2, q = t & 3;
        const float* wr = (o < 18) ? (wcls + o * 512) : (wbbox + (o - 18) * 512);
        float s = 0.f;
        int base = q * 128;
#pragma unroll 4
        for (int k2 = 0; k2 < 128; ++k2) s += x[base + k2] * wr[base + k2];
        part[o][q] = s;
    }
    __syncthreads();
    if (t < 54) {
        float b = (t < 18) ? bcls[t] : bbbox[t - 18];
        logit[t] = part[t][0] + part[t][1] + part[t][2] + part[t][3] + b;
    }
    __syncthreads();
    if (t < 9) {
        int a = t;
        float bg = logit[a], fg = logit[9 + a];
        float score = 1.f / (1.f + expf(bg - fg));
        float dx = logit[18 + 4 * a], dy = logit[19 + 4 * a];
        float dw = logit[20 + 4 * a], dh = logit[21 + 4 * a];
        int idx = pos * 9 + a;
        float ax1 = anchors[idx * 4 + 0], ay1 = anchors[idx * 4 + 1];
        float ax2 = anchors[idx * 4 + 2], ay2 = anchors[idx * 4 + 3];
        float aw = ax2 - ax1 + 1.f, ah = ay2 - ay1 + 1.f;
        float cx = ax1 + 0.5f * aw, cy = ay1 + 0.5f * ah;
        float pcx = dx * aw + cx, pcy = dy * ah + cy;
        float pw = expf(dw) * aw, ph = expf(dh) * ah;
        float x1 = fminf(fmaxf(pcx - 0.5f * pw, 0.f), 999.f);
        float y1 = fminf(fmaxf(pcy - 0.5f * ph, 0.f), 599.f);
        float x2 = fminf(fmaxf(pcx + 0.5f * pw, 0.f), 999.f);
        float y2 = fminf(fmaxf(pcy + 0.5f * ph, 0.f), 599.f);
        proposals[idx * 4 + 0] = x1; proposals[idx * 4 + 1] = y1;
        proposals[idx * 4 + 2] = x2; proposals[idx * 4 + 3] = y2;
        union { float f; unsigned int i; } sv; sv.f = score;
        keys[idx] = (((unsigned long long)sv.i) << 32) |
                    (unsigned long long)(0xFFFFFFFFu - (unsigned)idx);
    }
}

__global__ __launch_bounds__(256) void k_rank_partial(const unsigned long long* __restrict__ keys,
                                                      unsigned int* __restrict__ rpart) {
    __shared__ unsigned long long kc[1024];
    int i = blockIdx.x * 256 + threadIdx.x;
    int q = blockIdx.y;
    unsigned long long myk = (i < NANCH) ? keys[i] : 0xFFFFFFFFFFFFFFFFull;
    int j0 = q * QLEN;
    int j1 = j0 + QLEN; if (j1 > NANCH) j1 = NANCH;
    unsigned int cnt = 0;
    for (int base = j0; base < j1; base += 1024) {
        int nload = j1 - base; if (nload > 1024) nload = 1024;
        __syncthreads();
        for (int u = threadIdx.x; u < 1024; u += 256)
            kc[u] = (base + u < j1) ? keys[base + u] : 0ull;
        __syncthreads();
        for (int u = 0; u < nload; ++u)
            cnt += (kc[u] > myk) ? 1u : 0u;
    }
    if (i < NANCH) rpart[i * NQ + q] = cnt;
}

__global__ void k_zero_sboxes(float* __restrict__ sboxes) {
    int i = blockIdx.x * 256 + threadIdx.x;
    if (i < PRE * 4) sboxes[i] = 0.f;
}

__global__ void k_rank_scatter(const unsigned int* __restrict__ rpart,
                               const float* __restrict__ proposals,
                               float* __restrict__ sboxes) {
    int i = blockIdx.x * 256 + threadIdx.x;
    if (i >= NANCH) return;
    unsigned int r = 0;
#pragma unroll
    for (int q = 0; q < NQ; q++) r += rpart[i * NQ + q];
    if (r < PRE) {
        sboxes[r * 4 + 0] = proposals[i * 4 + 0];
        sboxes[r * 4 + 1] = proposals[i * 4 + 1];
        sboxes[r * 4 + 2] = proposals[i * 4 + 2];
        sboxes[r * 4 + 3] = proposals[i * 4 + 3];
    }
}

__global__ __launch_bounds__(64) void k_nms_mask(const float* __restrict__ sboxes,
                                                 unsigned long long* __restrict__ mask) {
    __shared__ float bx[64][4];
    int ib = blockIdx.x, jb = blockIdx.y;
    int lane = threadIdx.x;
    int j = jb * 64 + lane;
    if (j < PRE) {
        bx[lane][0] = sboxes[j * 4 + 0]; bx[lane][1] = sboxes[j * 4 + 1];
        bx[lane][2] = sboxes[j * 4 + 2]; bx[lane][3] = sboxes[j * 4 + 3];
    } else {
        bx[lane][0] = 3e8f; bx[lane][1] = 3e8f; bx[lane][2] = 3e8f; bx[lane][3] = 3e8f;
    }
    __syncthreads();
    int i = ib * 64 + lane;
    if (i >= PRE) return;
    float x1 = sboxes[i * 4 + 0], y1 = sboxes[i * 4 + 1];
    float x2 = sboxes[i * 4 + 2], y2 = sboxes[i * 4 + 3];
    float ar = (x2 - x1 + 1.f) * (y2 - y1 + 1.f);
    unsigned long long bits = 0;
#pragma unroll 4
    for (int u = 0; u < 64; u++) {
        int j2 = jb * 64 + u;
        float iw = fminf(x2, bx[u][2]) - fmaxf(x1, bx[u][0]) + 1.f;
        float ih = fminf(y2, bx[u][3]) - fmaxf(y1, bx[u][1]) + 1.f;
        iw = fmaxf(iw, 0.f); ih = fmaxf(ih, 0.f);
        float inter = iw * ih;
        float arj = (bx[u][2] - bx[u][0] + 1.f) * (bx[u][3] - bx[u][1] + 1.f);
        float iou = inter / (ar + arj - inter);
        if (iou > 0.7f && j2 > i) bits |= (1ull << u);
    }
    mask[(size_t)i * NWORD + jb] = bits;
}

// Greedy scan with speculative windowed prefetch.
// Rows are fetched in candidate-index order (addresses independent of scan state)
// into a double-buffered LDS window of 32 rows (768 B padded each), staged via
// global_load_lds w16 and kept in flight across raw s_barrier via counted vmcnt(6).
// All 4 waves run the serial greedy logic redundantly (identical data -> uniform
// control flow, no done-flag handshake). Bit-identical result to the old scan.
#define NMSW 32
#define NWIN 188                     // ceil(6000/32)
#define ROWPAD 768                   // 94*8=752 padded to 48*16
#define WINB (NMSW * ROWPAD)         // 24576
__global__ __launch_bounds__(256) void k_nms_scan(const unsigned long long* __restrict__ mask,
                                                  int* __restrict__ keep) {
    __shared__ __align__(16) char ldsw[2 * WINB];   // 48 KB double buffer
    const int t = threadIdx.x, wave = t >> 6, lane = t & 63;
    const char* mb = (const char*)mask;

    // 6 chunk descriptors per thread for window 0: global chunk g = (wave*6+k)*64+lane
    const char* src[6];
    int ldso[6];
#pragma unroll
    for (int k = 0; k < 6; ++k) {
        int g = (wave * 6 + k) * 64 + lane;       // 0..1535
        int row = g / 48, off = g - row * 48;
        src[k] = mb + (size_t)row * 752 + off * 16;
        ldso[k] = (wave * 6 + k) * 1024;           // wave-uniform LDS base per call
    }

    // prologue: window 0 -> buf0
#pragma unroll
    for (int k = 0; k < 6; ++k) gload16(src[k], ldsw + ldso[k]);
    asm volatile("s_waitcnt vmcnt(0)" ::: "memory");
    __builtin_amdgcn_s_barrier();
    asm volatile("" ::: "memory");

    unsigned long long rem0 = 0, rem1 = 0;
    int nk = 0;
    for (int w = 0; w < NWIN; ++w) {
        int cb = w & 1;
        if (w + 1 < NWIN) {
#pragma unroll
            for (int k = 0; k < 6; ++k)
                gload16(src[k] + (size_t)(w + 1) * (NMSW * 752), ldsw + (cb ^ 1) * WINB + ldso[k]);
            asm volatile("s_waitcnt vmcnt(6)" ::: "memory");   // window w complete; w+1 in flight
        } else {
            asm volatile("s_waitcnt vmcnt(0)" ::: "memory");
        }
        __builtin_amdgcn_s_barrier();
        asm volatile("" ::: "memory");

        // serial greedy over candidates [w*32, w*32+32) — run by ALL waves identically
        {
            int b = w >> 1;
            unsigned long long valid = (b == NWORD - 1) ? ((1ull << 48) - 1) : ~0ull;
            unsigned long long wmask = (w & 1) ? 0xFFFFFFFF00000000ull : 0x00000000FFFFFFFFull;
            unsigned long long rm = (b < 64) ? __shfl(rem0, b) : __shfl(rem1, b - 64);
            unsigned long long alive = ~rm & valid & wmask;
            const char* basep = ldsw + cb * WINB;
            while (alive) {
                int u = __ffsll((long long)alive) - 1;
                int i = b * 64 + u;
                if (wave == 0 && lane == 0) keep[nk] = i;
                ++nk;
                if (nk == POST) break;
                const unsigned long long* lrow =
                    (const unsigned long long*)(basep + (i - w * NMSW) * ROWPAD);
                unsigned long long w0 = lrow[lane];
                unsigned long long w1 = 0;
                if (lane < NWORD - 64) w1 = lrow[64 + lane];
                rem0 |= w0; rem1 |= w1;
                rm = (b < 64) ? __shfl(rem0, b) : __shfl(rem1, b - 64);
                alive = ~rm & valid & wmask & ((u == 63) ? 0ull : (~0ull << (u + 1)));
            }
        }
        if (nk >= POST) break;          // uniform across all waves
        asm volatile("" ::: "memory");
        __builtin_amdgcn_s_barrier();    // all waves done reading buf[cb] before reuse
        asm volatile("" ::: "memory");
    }
    asm volatile("s_waitcnt vmcnt(0)" ::: "memory");  // drain any speculative loads
    if (wave == 0)
        for (int k2 = nk + lane; k2 < POST; k2 += 64) keep[k2] = PRE - 1;
}

// headers: roi box at the start of each of the roi's 8 output chunks
__global__ __launch_bounds__(256) void k_gather_rois(const float* sboxes, const int* keep,
                                                     float* outF) {
    int t = threadIdx.x;
    float4 box[2];
    int nr = 0;
    for (int r = t; r < POST; r += 256) {
        int ki = keep[r];
        if (ki < 0) ki = 0; if (ki > PRE - 1) ki = PRE - 1;
        box[nr++] = *reinterpret_cast<const float4*>(sboxes + ki * 4);
    }
    __syncthreads();
    nr = 0;
    for (int r = t; r < POST; r += 256) {
        float4 b = box[nr++];
#pragma unroll
        for (int cg = 0; cg < 8; ++cg)
            *reinterpret_cast<float4*>(outF + (size_t)(r * 512 + cg * 64) * 49) = b;
    }
}

// FAST crop: coalesced featT reads (lane=channel) + LDS-staged coalesced writes.
// grid (POST, 2), block 256 = 4 waves; wave w handles cg = blockIdx.y*4+w.
__global__ __launch_bounds__(256) void k_crop_fast(const float* __restrict__ featT,
                                                   float* out) {
    __shared__ float lds[4][49 * 65];   // [wave][e*65 + c_local], padded vs bank conflicts
    int r = blockIdx.x;
    int w = threadIdx.x >> 6, lane = threadIdx.x & 63;
    int cg = blockIdx.y * 4 + w;
    int c = cg * 64 + lane;
    float* chunk = out + (size_t)(r * 512 + cg * 64) * 49;
    const float4 b = *reinterpret_cast<const float4*>(chunk);   // wave-uniform broadcast
    float x1 = b.x, y1 = b.y, x2 = b.z, y2 = b.w;
    float by1 = (y1 / 16.f) / 37.f, bx1 = (x1 / 16.f) / 62.f;
    float by2 = (y2 / 16.f) / 37.f, bx2 = (x2 / 16.f) / 62.f;
    float dyn = by2 - by1, dxn = bx2 - bx1;
    for (int e = 0; e < 49; ++e) {
        int oy = e / 7, ox = e - oy * 7;
        float vv[4];
#pragma unroll
        for (int dy = 0; dy < 2; ++dy) {
            int sy = 2 * oy + dy;
            float ty = (float)sy / 13.f;
            float ys = by1 * 37.f + (ty * dyn) * 37.f;
            float yf = floorf(ys);
            float wy = ys - yf;
            int y0  = (int)fminf(fmaxf(yf, 0.f), 37.f);
            int y1i = (int)fminf(fmaxf(yf + 1.f, 0.f), 37.f);
#pragma unroll
            for (int dxx = 0; dxx < 2; ++dxx) {
                int sx = 2 * ox + dxx;
                float tx = (float)sx / 13.f;
                float xs = bx1 * 62.f + (tx * dxn) * 62.f;
                float xf = floorf(xs);
                float wx = xs - xf;
                int x0  = (int)fminf(fmaxf(xf, 0.f), 62.f);
                int x1i = (int)fminf(fmaxf(xf + 1.f, 0.f), 62.f);
                float f00 = featT[(size_t)(y0 * 63 + x0) * 512 + c];
                float f01 = featT[(size_t)(y0 * 63 + x1i) * 512 + c];
                float f10 = featT[(size_t)(y1i * 63 + x0) * 512 + c];
                float f11 = featT[(size_t)(y1i * 63 + x1i) * 512 + c];
                vv[dy * 2 + dxx] = f00 * (1.f - wy) * (1.f - wx) + f01 * (1.f - wy) * wx +
                                   f10 * wy * (1.f - wx) + f11 * wy * wx;
            }
        }
        lds[w][e * 65 + lane] = fmaxf(fmaxf(vv[0], vv[1]), fmaxf(vv[2], vv[3]));
    }
    __syncthreads();
    // linear coalesced write of the wave's 64x49 chunk
    for (int i = lane; i < 64 * 49; i += 64) {
        int cl = i / 49, e = i - cl * 49;
        chunk[i] = lds[w][e * 65 + cl];
    }
}

// SLOW fallback crop (reads NCHW net) — used only if ws too small
__global__ __launch_bounds__(64) void k_crop_slow(const float* __restrict__ net,
                                                  float* out) {
    int r = blockIdx.x, cg = blockIdx.y;
    int lane = threadIdx.x;
    int c = cg * 64 + lane;
    const float4 b = *reinterpret_cast<const float4*>(out + (size_t)(r * 512 + cg * 64) * 49);
    float x1 = b.x, y1 = b.y, x2 = b.z, y2 = b.w;
    float by1 = (y1 / 16.f) / 37.f, bx1 = (x1 / 16.f) / 62.f;
    float by2 = (y2 / 16.f) / 37.f, bx2 = (x2 / 16.f) / 62.f;
    float dyn = by2 - by1, dxn = bx2 - bx1;
    const float* fc = net + (size_t)c * NPOS;
    float* orow = out + ((size_t)r * 512 + c) * 49;
    for (int e = 0; e < 49; ++e) {
        int oy = e / 7, ox = e - oy * 7;
        float vv[4];
#pragma unroll
        for (int dy = 0; dy < 2; ++dy) {
            int sy = 2 * oy + dy;
            float ty = (float)sy / 13.f;
            float ys = by1 * 37.f + (ty * dyn) * 37.f;
            float yf = floorf(ys);
            float wy = ys - yf;
            int y0  = (int)fminf(fmaxf(yf, 0.f), 37.f);
            int y1i = (int)fminf(fmaxf(yf + 1.f, 0.f), 37.f);
#pragma unroll
            for (int dxx = 0; dxx < 2; ++dxx) {
                int sx = 2 * ox + dxx;
                float tx = (float)sx / 13.f;
                float xs = bx1 * 62.f + (tx * dxn) * 62.f;
                float xf = floorf(xs);
                float wx = xs - xf;
                int x0  = (int)fminf(fmaxf(xf, 0.f), 62.f);
                int x1i = (int)fminf(fmaxf(xf + 1.f, 0.f), 62.f);
                float f00 = fc[y0 * 63 + x0];
                float f01 = fc[y0 * 63 + x1i];
                float f10 = fc[y1i * 63 + x0];
                float f11 = fc[y1i * 63 + x1i];
                vv[dy * 2 + dxx] = f00 * (1.f - wy) * (1.f - wx) + f01 * (1.f - wy) * wx +
                                   f10 * wy * (1.f - wx) + f11 * wy * wx;
            }
        }
        orow[e] = fmaxf(fmaxf(vv[0], vv[1]), fmaxf(vv[2], vv[3]));
    }
}

extern "C" void kernel_launch(void* const* d_in, const int* in_sizes, int n_in,
                              void* d_out, int out_size, void* d_ws, size_t ws_size,
                              hipStream_t stream) {
    auto find = [&](int count, int fallback) {
        for (int i = 0; i < n_in; ++i) if (in_sizes[i] == count) return i;
        return fallback;
    };
    const float* net   = (const float*)d_in[find(NPOS * CIN, 0)];
    const float* wrpn  = (const float*)d_in[find(512 * KK, 1)];
    const float* brpn  = (const float*)d_in[find(512, 2)];
    const float* wcls  = (const float*)d_in[find(18 * 512, 3)];
    const float* bcls  = (const float*)d_in[find(18, 4)];
    const float* wbbox = (const float*)d_in[find(36 * 512, 5)];
    const float* bbbox = (const float*)d_in[find(36, 6)];
    const float* anch  = (const float*)d_in[find(NANCH * 4, 7)];

    char* ob = (char*)d_out;
    _Float16* BH             = (_Float16*)(ob + OFF_BH);
    _Float16* BL             = (_Float16*)(ob + OFF_BL);
    unsigned long long* mask = (unsigned long long*)(ob + OFF_BH);   // aliases dead BH/BL
    float* P0                = (float*)(ob + OFF_P0);
    float* P1                = (float*)(ob + OFF_P1);
    float* sboxes            = (float*)(ob + OFF_SBOX);
    int* keep                = (int*)(ob + OFF_KEEP);
    unsigned long long* keys = (unsigned long long*)(ob + OFF_KEYS);
    float* proposals         = (float*)(ob + OFF_PROP);
    unsigned int* rpart      = (unsigned int*)(ob + OFF_RPART);
    _Float16* FPH            = (_Float16*)(ob + OFF_FPH);
    _Float16* FPL            = (_Float16*)(ob + OFF_FPL);
    float* outF              = (float*)d_out;

    // featT in d_ws if it fits (survives the output-overwriting crop -> fast path).
    // Fallback: alias dead-until-conv P0 region (pad_split consumes featT before conv).
    const bool ws_ok = (ws_size >= (size_t)FEATT_BYTES);
    float* featT = ws_ok ? (float*)d_ws : (float*)(ob + OFF_P0);

    hipLaunchKernelGGL(k_transpose_feat, dim3(75, 16), dim3(256), 0, stream, net, featT);
    hipLaunchKernelGGL(k_pad_split, dim3(5330), dim3(256), 0, stream, featT, FPH, FPL);
    hipLaunchKernelGGL(k_prep_wf16, dim3(9216), dim3(256), 0, stream, wrpn, BH, BL);
    hipLaunchKernelGGL(k_conv3_mfma, dim3(19, 8, 2), dim3(256), 0, stream, FPH, FPL, BH, BL, P0, P1);
    hipLaunchKernelGGL(k_heads, dim3(NPOS), dim3(256), 0, stream, P0, P1, brpn, wcls, bcls, wbbox, bbbox, anch, proposals, keys);
    hipLaunchKernelGGL(k_rank_partial, dim3(85, NQ), dim3(256), 0, stream, keys, rpart);
    hipLaunchKernelGGL(k_zero_sboxes, dim3((PRE * 4 + 255) / 256), dim3(256), 0, stream, sboxes);
    hipLaunchKernelGGL(k_rank_scatter, dim3(85), dim3(256), 0, stream, rpart, proposals, sboxes);
    hipLaunchKernelGGL(k_nms_mask, dim3(NWORD, NWORD), dim3(64), 0, stream, sboxes, mask);
    hipLaunchKernelGGL(k_nms_scan, dim3(1), dim3(64 * 4), 0, stream, mask, keep);
    hipLaunchKernelGGL(k_gather_rois, dim3(1), dim3(256), 0, stream, sboxes, keep, outF);
    if (ws_ok)
        hipLaunchKernelGGL(k_crop_fast, dim3(POST, 2), dim3(256), 0, stream, featT, outF);
    else
        hipLaunchKernelGGL(k_crop_slow, dim3(POST, 8), dim3(64), 0, stream, net, outF);
}